// Round 8
// baseline (86.911 us; speedup 1.0000x reference)
//
#include <hip/hip_runtime.h>
#include <hip/hip_bf16.h>

typedef __bf16 bf16_t;
typedef __attribute__((ext_vector_type(8))) __bf16 bf16x8;
typedef __attribute__((ext_vector_type(4))) __bf16 bf16x4;
typedef __attribute__((ext_vector_type(4))) float f32x4;

#define AS1 __attribute__((address_space(1)))
#define AS3 __attribute__((address_space(3)))

__device__ __forceinline__ void gload_lds16(const void* g, void* l) {
  __builtin_amdgcn_global_load_lds((const AS1 void*)g, (AS3 void*)l, 16, 0, 0);
}

// ---------------- prep: all transposes in one flat-grid kernel ----------------
__global__ void __launch_bounds__(256) prep_kernel(
    const float* __restrict__ x, const float* __restrict__ w0,
    const float* __restrict__ w1, const float* __restrict__ w2,
    const float* __restrict__ w3, bf16_t* __restrict__ xr, bf16_t* __restrict__ t0,
    bf16_t* __restrict__ t1, bf16_t* __restrict__ t2, bf16_t* __restrict__ t3) {
  __shared__ float tile[32][33];
  const int tx = threadIdx.x, ty = threadIdx.y;
  int t = blockIdx.x;
  const float* src;
  bf16_t* dst;
  int ld_src, ld_dst, r0, c0;
  if (t < 1024) {
    int z = t >> 8, rem = t & 255;
    src = (z == 0) ? w0 : (z == 1) ? w1 : (z == 2) ? w2 : w3;
    dst = (z == 0) ? t0 : (z == 1) ? t1 : (z == 2) ? t2 : t3;
    ld_src = 512; ld_dst = 512;
    r0 = (rem & 15) * 32; c0 = (rem >> 4) * 32;
  } else {
    t -= 1024;
    int b = t >> 9, rem = t & 511;
    src = x + (size_t)b * 512 * 1024;
    dst = xr + (size_t)b * 1024 * 512;
    ld_src = 1024; ld_dst = 512;
    r0 = (rem & 15) * 32; c0 = (rem >> 4) * 32;
  }
#pragma unroll
  for (int i = 0; i < 32; i += 8)
    tile[ty + i][tx] = src[(r0 + ty + i) * ld_src + c0 + tx];
  __syncthreads();
#pragma unroll
  for (int i = 0; i < 32; i += 8)
    dst[(c0 + ty + i) * ld_dst + r0 + tx] = (bf16_t)tile[tx][ty + i];
}

// ------- 128x128xK=512 NT-GEMM mainloop, QUAD-buffered, depth-2 prefetch -------
// T2 swizzle (rule 21): LDS dest linear (global_load_lds), global SOURCE chunk
// pre-permuted chunk^((row>>1)&3), fragment reads apply the same XOR.
// One barrier per phase: {issue t+2 -> buf[(t+2)&3]; vmcnt(8); s_barrier; compute buf[t&3]}.
__device__ __forceinline__ void gemm_nt_128x128_p4(const bf16_t* __restrict__ Abase,
                                                   const bf16_t* __restrict__ Bbase,
                                                   bf16_t (*As)[128 * 32],
                                                   bf16_t (*Bs)[128 * 32],
                                                   f32x4 acc[4][4]) {
  const int tid = threadIdx.x;
  const int lane = tid & 63;
  const int wid = tid >> 6;
  const int wr = wid >> 1, wc = wid & 1;
  const int lrow = lane & 15;
  const int kgrp = lane >> 4;
  const int r0 = tid >> 2;        // 0..63: row within 64-row chunk
  const int cdst = (tid & 3) * 16;                         // LDS dest chunk (linear)
  const int csrc = (((tid & 3) ^ ((r0 >> 1) & 3))) * 16;   // swizzled global source chunk
  const int rsw = (lrow >> 1) & 3;                          // read-side XOR

  // prologue: issue tiles 0 and 1
#pragma unroll
  for (int p = 0; p < 2; ++p) {
    const int kt = p * 32;
#pragma unroll
    for (int j = 0; j < 2; ++j) {
      int row = j * 64 + r0;
      gload_lds16((const char*)(Abase + row * 512 + kt) + csrc, (char*)As[p] + row * 64 + cdst);
    }
#pragma unroll
    for (int j = 0; j < 2; ++j) {
      int row = j * 64 + r0;
      gload_lds16((const char*)(Bbase + row * 512 + kt) + csrc, (char*)Bs[p] + row * 64 + cdst);
    }
  }

  for (int t = 0; t < 16; ++t) {
    const int cur = t & 3;
    if (t < 14) {
      const int nxt = (t + 2) & 3;
      const int kt = (t + 2) * 32;
#pragma unroll
      for (int j = 0; j < 2; ++j) {
        int row = j * 64 + r0;
        gload_lds16((const char*)(Abase + row * 512 + kt) + csrc,
                    (char*)As[nxt] + row * 64 + cdst);
      }
#pragma unroll
      for (int j = 0; j < 2; ++j) {
        int row = j * 64 + r0;
        gload_lds16((const char*)(Bbase + row * 512 + kt) + csrc,
                    (char*)Bs[nxt] + row * 64 + cdst);
      }
      asm volatile("s_waitcnt vmcnt(8)" ::: "memory");   // tile t complete
    } else if (t == 14) {
      asm volatile("s_waitcnt vmcnt(4)" ::: "memory");
    } else {
      asm volatile("s_waitcnt vmcnt(0)" ::: "memory");
    }
    __builtin_amdgcn_sched_barrier(0);
    __builtin_amdgcn_s_barrier();

    bf16x8 a[4], b[4];
#pragma unroll
    for (int mf = 0; mf < 4; ++mf)
      a[mf] = *(const bf16x8*)(As[cur] + (wr * 64 + mf * 16 + lrow) * 32 + (kgrp ^ rsw) * 8);
#pragma unroll
    for (int nf = 0; nf < 4; ++nf)
      b[nf] = *(const bf16x8*)(Bs[cur] + (wc * 64 + nf * 16 + lrow) * 32 + (kgrp ^ rsw) * 8);
    __builtin_amdgcn_s_setprio(1);
#pragma unroll
    for (int mf = 0; mf < 4; ++mf)
#pragma unroll
      for (int nf = 0; nf < 4; ++nf)
        acc[mf][nf] = __builtin_amdgcn_mfma_f32_16x16x32_bf16(a[mf], b[nf], acc[mf][nf], 0, 0, 0);
    __builtin_amdgcn_s_setprio(0);
  }
}

// ---------------- QKV projection: persistent 512-block grid, 768 tiles ----------------
__global__ void __launch_bounds__(256, 2) gemm_qkv_kernel(
    const bf16_t* __restrict__ xr, const bf16_t* __restrict__ wqT,
    const bf16_t* __restrict__ wkT, const bf16_t* __restrict__ wvT,
    const float* __restrict__ bq, const float* __restrict__ bk,
    const float* __restrict__ bv, bf16_t* __restrict__ qo, bf16_t* __restrict__ ko,
    bf16_t* __restrict__ vto) {
  __shared__ bf16_t As[4][128 * 32];
  __shared__ bf16_t Bs[4][128 * 32];
  const int lane = threadIdx.x & 63, wid = threadIdx.x >> 6;
  const int lrow = lane & 15, kgrp = lane >> 4;
  const int wr = wid >> 1, wc = wid & 1;
  const float qscale = 0.044194173824159216f * 1.4426950408889634f;  // 1/sqrt(512)*log2e

#pragma unroll 1
  for (int it = 0; it < 2; ++it) {
    const int tile = blockIdx.x + it * 512;
    if (tile >= 768) break;
    const int bn = tile & 3, bm = (tile >> 2) & 63, z = tile >> 8;
    const bf16_t* wT = (z == 0) ? wqT : (z == 1) ? wkT : wvT;
    const float* bias = (z == 0) ? bq : (z == 1) ? bk : bv;
    f32x4 acc[4][4] = {};
    gemm_nt_128x128_p4(xr + bm * 128 * 512, wT + bn * 128 * 512, As, Bs, acc);
    const int row0 = bm * 128 + wr * 64;
    const int col0 = bn * 128 + wc * 64;
    if (z == 2) {
      // V written directly transposed: vt[(b*8+h)*64 + d][s], 4 consecutive s per lane
#pragma unroll
      for (int mf = 0; mf < 4; ++mf)
#pragma unroll
        for (int nf = 0; nf < 4; ++nf) {
          int n = col0 + nf * 16 + lrow;
          int h = n >> 6, d = n & 63;
          float bb = bias[n];
          int m0 = row0 + mf * 16 + kgrp * 4;
          int b = m0 >> 10, s = m0 & 1023;
          bf16x4 pk;
#pragma unroll
          for (int r = 0; r < 4; ++r) pk[r] = (bf16_t)(acc[mf][nf][r] + bb);
          *(bf16x4*)(vto + (((size_t)(b * 8 + h) * 64 + d) * 1024 + s)) = pk;
        }
    } else {
      bf16_t* out = (z == 0) ? qo : ko;
      const float sc = (z == 0) ? qscale : 1.0f;
#pragma unroll
      for (int mf = 0; mf < 4; ++mf)
#pragma unroll
        for (int nf = 0; nf < 4; ++nf) {
          int n = col0 + nf * 16 + lrow;
          int h = n >> 6, d = n & 63;
          float bb = bias[n];
#pragma unroll
          for (int r = 0; r < 4; ++r) {
            int m = row0 + mf * 16 + kgrp * 4 + r;
            int b = m >> 10, s = m & 1023;
            out[((b * 8 + h) * 1024 + s) * 64 + d] = (bf16_t)((acc[mf][nf][r] + bb) * sc);
          }
        }
    }
  }
}

// ---------------- flash attention: quad-buffered K/V, depth-2, 1 barrier/phase ----
__global__ void __launch_bounds__(256, 2) attn_kernel(const bf16_t* __restrict__ q,
                                                      const bf16_t* __restrict__ k,
                                                      const bf16_t* __restrict__ vt,
                                                      bf16_t* __restrict__ attn_out) {
  __shared__ char Ks[4][8192];   // [64 key][64 d] bf16, 128B rows, 16B-chunk swizzled
  __shared__ char Vs[4][8192];   // [64 d][64 key] bf16, 128B rows, swizzled
  __shared__ char Ps[4][4096];   // per-wave P [32 q][64 key] bf16, swizzled
  const int tid = threadIdx.x;
  const int lane = tid & 63, wid = tid >> 6;
  const int lrow = lane & 15, kgrp = lane >> 4;
  const int bh = blockIdx.x, qb = blockIdx.y;
  const int b = bh >> 3, h = bh & 7;

  const char* khb = (const char*)(k + (size_t)bh * 1024 * 64);
  const char* vthb = (const char*)(vt + (size_t)bh * 64 * 1024);
  const bf16_t* qh = q + (size_t)bh * 1024 * 64;

  const int qbase = qb * 128 + wid * 32;
  bf16x8 qa[2][2];
#pragma unroll
  for (int qf = 0; qf < 2; ++qf) {
    int qrow = qbase + qf * 16 + lrow;
    qa[qf][0] = *(const bf16x8*)(qh + qrow * 64 + kgrp * 8);
    qa[qf][1] = *(const bf16x8*)(qh + qrow * 64 + 32 + kgrp * 8);
  }

  char* Pw = Ps[wid];
  const int srow = tid >> 3;
  const int sc2 = tid & 7;

  float l_part[2] = {0.f, 0.f};
  f32x4 o[2][4] = {};

  // prologue: stage tiles 0 and 1
#pragma unroll
  for (int p = 0; p < 2; ++p) {
    const char* kg = khb + p * (64 * 128);
    const char* vg = vthb + p * 128;
#pragma unroll
    for (int j = 0; j < 2; ++j) {
      int row = j * 32 + srow;
      gload_lds16(kg + row * 128 + ((sc2 ^ (row & 7)) * 16), Ks[p] + j * 4096 + tid * 16);
    }
#pragma unroll
    for (int j = 0; j < 2; ++j) {
      int row = j * 32 + srow;
      gload_lds16(vg + row * 2048 + ((sc2 ^ (row & 7)) * 16), Vs[p] + j * 4096 + tid * 16);
    }
  }

  for (int t = 0; t < 16; ++t) {
    const int cur = t & 3;
    if (t < 14) {
      const int nxt = (t + 2) & 3;
      const char* kg = khb + (t + 2) * (64 * 128);
      const char* vg = vthb + (t + 2) * 128;
#pragma unroll
      for (int j = 0; j < 2; ++j) {
        int row = j * 32 + srow;
        gload_lds16(kg + row * 128 + ((sc2 ^ (row & 7)) * 16),
                    Ks[nxt] + j * 4096 + tid * 16);
      }
#pragma unroll
      for (int j = 0; j < 2; ++j) {
        int row = j * 32 + srow;
        gload_lds16(vg + row * 2048 + ((sc2 ^ (row & 7)) * 16),
                    Vs[nxt] + j * 4096 + tid * 16);
      }
      asm volatile("s_waitcnt vmcnt(8)" ::: "memory");   // tile t complete
    } else if (t == 14) {
      asm volatile("s_waitcnt vmcnt(4)" ::: "memory");
    } else {
      asm volatile("s_waitcnt vmcnt(0)" ::: "memory");
    }
    __builtin_amdgcn_sched_barrier(0);
    __builtin_amdgcn_s_barrier();

    const char* Kc = Ks[cur];
    const char* Vc = Vs[cur];

    // QK^T (swapped): sa[qf][c] col(lane&15)=q-within-16, row(kgrp*4+r)=key
    f32x4 sa[2][4] = {};
    __builtin_amdgcn_s_setprio(1);
#pragma unroll
    for (int c = 0; c < 4; ++c) {
      int krow = c * 16 + lrow;
      bf16x8 k0 = *(const bf16x8*)(Kc + krow * 128 + ((kgrp ^ (krow & 7)) * 16));
      bf16x8 k1 = *(const bf16x8*)(Kc + krow * 128 + (((4 + kgrp) ^ (krow & 7)) * 16));
#pragma unroll
      for (int qf = 0; qf < 2; ++qf) {
        sa[qf][c] = __builtin_amdgcn_mfma_f32_16x16x32_bf16(k0, qa[qf][0], sa[qf][c], 0, 0, 0);
        sa[qf][c] = __builtin_amdgcn_mfma_f32_16x16x32_bf16(k1, qa[qf][1], sa[qf][c], 0, 0, 0);
      }
    }
    __builtin_amdgcn_s_setprio(0);

    // softmax numerator + P store (per-wave tile [32 q][64 key], swizzled)
#pragma unroll
    for (int qf = 0; qf < 2; ++qf) {
      int prow = qf * 16 + lrow;
      float rs = 0.f;
#pragma unroll
      for (int c = 0; c < 4; ++c) {
        bf16x4 pk;
#pragma unroll
        for (int r = 0; r < 4; ++r) {
          float p = exp2f(sa[qf][c][r]);
          rs += p;
          pk[r] = (bf16_t)p;
        }
        int chunk = (c * 2 + (kgrp >> 1)) ^ (prow & 7);
        *(bf16x4*)(Pw + prow * 128 + chunk * 16 + (kgrp & 1) * 8) = pk;
      }
      l_part[qf] += rs;
    }

    // PV
    __builtin_amdgcn_s_setprio(1);
#pragma unroll
    for (int kk = 0; kk < 2; ++kk) {
      bf16x8 pa[2];
#pragma unroll
      for (int qf = 0; qf < 2; ++qf) {
        int prow = qf * 16 + lrow;
        int pchunk = (kk * 4 + kgrp) ^ (prow & 7);
        pa[qf] = *(const bf16x8*)(Pw + prow * 128 + pchunk * 16);
      }
#pragma unroll
      for (int nfo = 0; nfo < 4; ++nfo) {
        int vrow = nfo * 16 + lrow;
        int vchunk = (kk * 4 + kgrp) ^ (vrow & 7);
        bf16x8 vb = *(const bf16x8*)(Vc + vrow * 128 + vchunk * 16);
#pragma unroll
        for (int qf = 0; qf < 2; ++qf)
          o[qf][nfo] = __builtin_amdgcn_mfma_f32_16x16x32_bf16(pa[qf], vb, o[qf][nfo], 0, 0, 0);
      }
    }
    __builtin_amdgcn_s_setprio(0);
  }

  // epilogue: denominator reduce + transpose to O orientation + store
#pragma unroll
  for (int qf = 0; qf < 2; ++qf) {
    l_part[qf] += __shfl_xor(l_part[qf], 16, 64);
    l_part[qf] += __shfl_xor(l_part[qf], 32, 64);
  }
#pragma unroll
  for (int qf = 0; qf < 2; ++qf)
#pragma unroll
    for (int r = 0; r < 4; ++r) {
      float inv = 1.0f / __shfl(l_part[qf], kgrp * 4 + r, 64);
      int s = qbase + qf * 16 + kgrp * 4 + r;
#pragma unroll
      for (int nfo = 0; nfo < 4; ++nfo) {
        int d = nfo * 16 + lrow;
        attn_out[((b * 1024 + s) * 8 + h) * 64 + d] = (bf16_t)(o[qf][nfo][r] * inv);
      }
    }
}

// ---------------- out-proj (transposed): woT x attn + x -> out ----------------
__global__ void __launch_bounds__(256, 2) gemm_out_kernel(const bf16_t* __restrict__ woT,
                                                          const bf16_t* __restrict__ attn,
                                                          const float* __restrict__ x,
                                                          const float* __restrict__ bo,
                                                          float* __restrict__ out) {
  __shared__ bf16_t As[4][128 * 32];
  __shared__ bf16_t Bs[4][128 * 32];
  const int bn = blockIdx.x, bm = blockIdx.y;
  f32x4 acc[4][4] = {};
  gemm_nt_128x128_p4(woT + bm * 128 * 512, attn + bn * 128 * 512, As, Bs, acc);
  const int lane = threadIdx.x & 63, wid = threadIdx.x >> 6;
  const int wr = wid >> 1, wc = wid & 1;
  const int c0 = bm * 128 + wr * 64;
  const int s0g = bn * 128 + wc * 64;
#pragma unroll
  for (int mf = 0; mf < 4; ++mf)
#pragma unroll
    for (int r = 0; r < 4; ++r) {
      int c = c0 + mf * 16 + (lane >> 4) * 4 + r;
      float bias = bo[c];
#pragma unroll
      for (int nf = 0; nf < 4; ++nf) {
        int n = s0g + nf * 16 + (lane & 15);
        int b = n >> 10, s = n & 1023;
        int idx = (b * 512 + c) * 1024 + s;
        out[idx] = x[idx] + acc[mf][nf][r] + bias;
      }
    }
}

extern "C" void kernel_launch(void* const* d_in, const int* in_sizes, int n_in,
                              void* d_out, int out_size, void* d_ws, size_t ws_size,
                              hipStream_t stream) {
  const float* x  = (const float*)d_in[0];
  const float* wq = (const float*)d_in[1];
  const float* bq = (const float*)d_in[2];
  const float* wk = (const float*)d_in[3];
  const float* bk = (const float*)d_in[4];
  const float* wv = (const float*)d_in[5];
  const float* bv = (const float*)d_in[6];
  const float* wo = (const float*)d_in[7];
  const float* bo = (const float*)d_in[8];
  float* out = (float*)d_out;

  char* ws = (char*)d_ws;
  const size_t SZ_XR = (size_t)8192 * 512 * 2;         // 8 MB
  const size_t SZ_W  = (size_t)512 * 512 * 2;          // 0.5 MB
  const size_t SZ_T  = (size_t)8 * 8 * 1024 * 64 * 2;  // 8 MB
  bf16_t* xr   = (bf16_t*)(ws);                        // dead after QKV GEMM
  bf16_t* wqT  = (bf16_t*)(ws + SZ_XR);
  bf16_t* wkT  = (bf16_t*)(ws + SZ_XR + SZ_W);
  bf16_t* wvT  = (bf16_t*)(ws + SZ_XR + 2 * SZ_W);
  bf16_t* woT  = (bf16_t*)(ws + SZ_XR + 3 * SZ_W);
  bf16_t* qd   = (bf16_t*)(ws + SZ_XR + 4 * SZ_W);
  bf16_t* kd   = (bf16_t*)(ws + SZ_XR + 4 * SZ_W + SZ_T);
  bf16_t* vtd  = (bf16_t*)(ws + SZ_XR + 4 * SZ_W + 2 * SZ_T);
  bf16_t* attn = (bf16_t*)(ws);                        // alias xr (dead by attn time)

  prep_kernel<<<dim3(5120), dim3(32, 8), 0, stream>>>(x, wq, wk, wv, wo, xr, wqT, wkT,
                                                      wvT, woT);
  gemm_qkv_kernel<<<dim3(512), 256, 0, stream>>>(xr, wqT, wkT, wvT, bq, bk, bv,
                                                 qd, kd, vtd);
  attn_kernel<<<dim3(64, 8), 256, 0, stream>>>(qd, kd, vtd, attn);
  gemm_out_kernel<<<dim3(64, 4), 256, 0, stream>>>(woT, attn, x, bo, out);
}

// Round 9
// 85.258 us; speedup vs baseline: 1.0194x; 1.0194x over previous
//
#include <hip/hip_runtime.h>
#include <hip/hip_bf16.h>

typedef __bf16 bf16_t;
typedef __attribute__((ext_vector_type(8))) __bf16 bf16x8;
typedef __attribute__((ext_vector_type(4))) __bf16 bf16x4;
typedef __attribute__((ext_vector_type(4))) float f32x4;

#define AS1 __attribute__((address_space(1)))
#define AS3 __attribute__((address_space(3)))

__device__ __forceinline__ void gload_lds16(const void* g, void* l) {
  __builtin_amdgcn_global_load_lds((const AS1 void*)g, (AS3 void*)l, 16, 0, 0);
}

// ---------------- prep: all transposes in one flat-grid kernel ----------------
__global__ void __launch_bounds__(256) prep_kernel(
    const float* __restrict__ x, const float* __restrict__ w0,
    const float* __restrict__ w1, const float* __restrict__ w2,
    const float* __restrict__ w3, bf16_t* __restrict__ xr, bf16_t* __restrict__ t0,
    bf16_t* __restrict__ t1, bf16_t* __restrict__ t2, bf16_t* __restrict__ t3) {
  __shared__ float tile[32][33];
  const int tx = threadIdx.x, ty = threadIdx.y;
  int t = blockIdx.x;
  const float* src;
  bf16_t* dst;
  int ld_src, ld_dst, r0, c0;
  if (t < 1024) {
    int z = t >> 8, rem = t & 255;
    src = (z == 0) ? w0 : (z == 1) ? w1 : (z == 2) ? w2 : w3;
    dst = (z == 0) ? t0 : (z == 1) ? t1 : (z == 2) ? t2 : t3;
    ld_src = 512; ld_dst = 512;
    r0 = (rem & 15) * 32; c0 = (rem >> 4) * 32;
  } else {
    t -= 1024;
    int b = t >> 9, rem = t & 511;
    src = x + (size_t)b * 512 * 1024;
    dst = xr + (size_t)b * 1024 * 512;
    ld_src = 1024; ld_dst = 512;
    r0 = (rem & 15) * 32; c0 = (rem >> 4) * 32;
  }
#pragma unroll
  for (int i = 0; i < 32; i += 8)
    tile[ty + i][tx] = src[(r0 + ty + i) * ld_src + c0 + tx];
  __syncthreads();
#pragma unroll
  for (int i = 0; i < 32; i += 8)
    dst[(c0 + ty + i) * ld_dst + r0 + tx] = (bf16_t)tile[tx][ty + i];
}

// ------- 128x128xK=512 NT-GEMM mainloop, QUAD-buffered, depth-2 (round-7) -------
__device__ __forceinline__ void gemm_nt_128x128_p4(const bf16_t* __restrict__ Abase,
                                                   const bf16_t* __restrict__ Bbase,
                                                   bf16_t (*As)[128 * 32],
                                                   bf16_t (*Bs)[128 * 32],
                                                   f32x4 acc[4][4]) {
  const int tid = threadIdx.x;
  const int lane = tid & 63;
  const int wid = tid >> 6;
  const int wr = wid >> 1, wc = wid & 1;
  const int lrow = lane & 15;
  const int kgrp = lane >> 4;
  const int r0 = tid >> 2;
  const int cb = (tid & 3) * 16;

#pragma unroll
  for (int p = 0; p < 2; ++p) {
    const int kt = p * 32;
#pragma unroll
    for (int j = 0; j < 2; ++j) {
      int row = j * 64 + r0;
      gload_lds16((const char*)(Abase + row * 512 + kt) + cb, (char*)As[p] + row * 64 + cb);
    }
#pragma unroll
    for (int j = 0; j < 2; ++j) {
      int row = j * 64 + r0;
      gload_lds16((const char*)(Bbase + row * 512 + kt) + cb, (char*)Bs[p] + row * 64 + cb);
    }
  }

  for (int t = 0; t < 16; ++t) {
    const int cur = t & 3;
    if (t < 14) {
      const int nxt = (t + 2) & 3;
      const int kt = (t + 2) * 32;
#pragma unroll
      for (int j = 0; j < 2; ++j) {
        int row = j * 64 + r0;
        gload_lds16((const char*)(Abase + row * 512 + kt) + cb,
                    (char*)As[nxt] + row * 64 + cb);
      }
#pragma unroll
      for (int j = 0; j < 2; ++j) {
        int row = j * 64 + r0;
        gload_lds16((const char*)(Bbase + row * 512 + kt) + cb,
                    (char*)Bs[nxt] + row * 64 + cb);
      }
      asm volatile("s_waitcnt vmcnt(8)" ::: "memory");
    } else if (t == 14) {
      asm volatile("s_waitcnt vmcnt(4)" ::: "memory");
    } else {
      asm volatile("s_waitcnt vmcnt(0)" ::: "memory");
    }
    __builtin_amdgcn_sched_barrier(0);
    __builtin_amdgcn_s_barrier();

    bf16x8 a[4], b[4];
#pragma unroll
    for (int mf = 0; mf < 4; ++mf)
      a[mf] = *(const bf16x8*)(As[cur] + (wr * 64 + mf * 16 + lrow) * 32 + kgrp * 8);
#pragma unroll
    for (int nf = 0; nf < 4; ++nf)
      b[nf] = *(const bf16x8*)(Bs[cur] + (wc * 64 + nf * 16 + lrow) * 32 + kgrp * 8);
    __builtin_amdgcn_s_setprio(1);
#pragma unroll
    for (int mf = 0; mf < 4; ++mf)
#pragma unroll
      for (int nf = 0; nf < 4; ++nf)
        acc[mf][nf] = __builtin_amdgcn_mfma_f32_16x16x32_bf16(a[mf], b[nf], acc[mf][nf], 0, 0, 0);
    __builtin_amdgcn_s_setprio(0);
  }
}

// ------- 128x256xK=512 NT-GEMM mainloop, TRIPLE-buffered, depth-2, 1 barrier/phase ---
// Ordering per phase t: {barrier; issue t+2 -> buf[(t+2)%3]; compute buf[t%3]; vmcnt(6)}.
// barrier(t) guarantees all waves finished compute(t-1) before any DMA targets
// buf[(t-1)%3]; each wave's vmcnt(6) at end of body(t-1) lands tile t before the
// barrier that precedes compute(t).
__device__ __forceinline__ void gemm_nt_128x256_p3(const bf16_t* __restrict__ Abase,
                                                   const bf16_t* __restrict__ Bbase,
                                                   bf16_t (*As)[128 * 32],
                                                   bf16_t (*Bs)[256 * 32],
                                                   f32x4 acc[4][8]) {
  const int tid = threadIdx.x;
  const int lane = tid & 63;
  const int wid = tid >> 6;
  const int wr = wid >> 1, wc = wid & 1;
  const int lrow = lane & 15;
  const int kgrp = lane >> 4;
  const int r0 = tid >> 2;
  const int cb = (tid & 3) * 16;

  // prologue: issue tiles 0,1 (6 loads each)
#pragma unroll
  for (int p = 0; p < 2; ++p) {
    const int kt = p * 32;
#pragma unroll
    for (int j = 0; j < 2; ++j) {
      int row = j * 64 + r0;
      gload_lds16((const char*)(Abase + row * 512 + kt) + cb, (char*)As[p] + row * 64 + cb);
    }
#pragma unroll
    for (int j = 0; j < 4; ++j) {
      int row = j * 64 + r0;
      gload_lds16((const char*)(Bbase + row * 512 + kt) + cb, (char*)Bs[p] + row * 64 + cb);
    }
  }
  asm volatile("s_waitcnt vmcnt(6)" ::: "memory");  // tile 0 landed (own loads)
  __builtin_amdgcn_sched_barrier(0);

  int cur = 0, nxt = 2;
  for (int t = 0; t < 16; ++t) {
    __builtin_amdgcn_s_barrier();
    __builtin_amdgcn_sched_barrier(0);
    if (t < 14) {
      const int kt = (t + 2) * 32;
#pragma unroll
      for (int j = 0; j < 2; ++j) {
        int row = j * 64 + r0;
        gload_lds16((const char*)(Abase + row * 512 + kt) + cb,
                    (char*)As[nxt] + row * 64 + cb);
      }
#pragma unroll
      for (int j = 0; j < 4; ++j) {
        int row = j * 64 + r0;
        gload_lds16((const char*)(Bbase + row * 512 + kt) + cb,
                    (char*)Bs[nxt] + row * 64 + cb);
      }
    }

    bf16x8 a[4], b[8];
#pragma unroll
    for (int mf = 0; mf < 4; ++mf)
      a[mf] = *(const bf16x8*)(As[cur] + (wr * 64 + mf * 16 + lrow) * 32 + kgrp * 8);
#pragma unroll
    for (int nf = 0; nf < 8; ++nf)
      b[nf] = *(const bf16x8*)(Bs[cur] + (wc * 128 + nf * 16 + lrow) * 32 + kgrp * 8);
    __builtin_amdgcn_s_setprio(1);
#pragma unroll
    for (int mf = 0; mf < 4; ++mf)
#pragma unroll
      for (int nf = 0; nf < 8; ++nf)
        acc[mf][nf] = __builtin_amdgcn_mfma_f32_16x16x32_bf16(a[mf], b[nf], acc[mf][nf], 0, 0, 0);
    __builtin_amdgcn_s_setprio(0);
    if (t < 14) {
      asm volatile("s_waitcnt vmcnt(6)" ::: "memory");   // tile t+1 landed
    } else {
      asm volatile("s_waitcnt vmcnt(0)" ::: "memory");
    }
    __builtin_amdgcn_sched_barrier(0);
    cur = (cur == 2) ? 0 : cur + 1;
    nxt = (nxt == 2) ? 0 : nxt + 1;
  }
}

// ---------------- QKV projection: 128x256 tiles, wq/wk/wv as one [1536][512] ---------
// grid (6 bn, 64 bm) = 384 blocks, 2/CU -> all co-resident, no tail.
__global__ void __launch_bounds__(256, 2) gemm_qkv_kernel(
    const bf16_t* __restrict__ xr, const bf16_t* __restrict__ wT /* [1536][512] */,
    const float* __restrict__ bq, const float* __restrict__ bk,
    const float* __restrict__ bv, bf16_t* __restrict__ qo, bf16_t* __restrict__ ko,
    bf16_t* __restrict__ vto) {
  __shared__ bf16_t As[3][128 * 32];
  __shared__ bf16_t Bs[3][256 * 32];
  const int bn = blockIdx.x, bm = blockIdx.y;
  const int z = bn >> 1;  // 256-wide tile lies within one of q/k/v
  const float* bias = (z == 0) ? bq : (z == 1) ? bk : bv;
  f32x4 acc[4][8] = {};
  gemm_nt_128x256_p3(xr + bm * 128 * 512, wT + (size_t)bn * 256 * 512, As, Bs, acc);
  const int lane = threadIdx.x & 63, wid = threadIdx.x >> 6;
  const int lrow = lane & 15, kgrp = lane >> 4;
  const int wr = wid >> 1, wc = wid & 1;
  const int row0 = bm * 128 + wr * 64;
  const int col0 = bn * 256 + wc * 128;
  const float qscale = 0.044194173824159216f * 1.4426950408889634f;  // 1/sqrt(512)*log2e
  if (z == 2) {
    // V written directly transposed: vt[(b*8+h)*64 + d][s], 4 consecutive s per lane
#pragma unroll
    for (int mf = 0; mf < 4; ++mf)
#pragma unroll
      for (int nf = 0; nf < 8; ++nf) {
        int nl = (col0 + nf * 16 + lrow) & 511;
        int h = nl >> 6, d = nl & 63;
        float bb = bias[nl];
        int m0 = row0 + mf * 16 + kgrp * 4;
        int b = m0 >> 10, s = m0 & 1023;
        bf16x4 pk;
#pragma unroll
        for (int r = 0; r < 4; ++r) pk[r] = (bf16_t)(acc[mf][nf][r] + bb);
        *(bf16x4*)(vto + (((size_t)(b * 8 + h) * 64 + d) * 1024 + s)) = pk;
      }
  } else {
    bf16_t* out = (z == 0) ? qo : ko;
    const float sc = (z == 0) ? qscale : 1.0f;
#pragma unroll
    for (int mf = 0; mf < 4; ++mf)
#pragma unroll
      for (int nf = 0; nf < 8; ++nf) {
        int nl = (col0 + nf * 16 + lrow) & 511;
        int h = nl >> 6, d = nl & 63;
        float bb = bias[nl];
#pragma unroll
        for (int r = 0; r < 4; ++r) {
          int m = row0 + mf * 16 + kgrp * 4 + r;
          int b = m >> 10, s = m & 1023;
          out[((b * 8 + h) * 1024 + s) * 64 + d] = (bf16_t)((acc[mf][nf][r] + bb) * sc);
        }
      }
  }
}

// ---------------- flash attention: quad-buffered K/V, depth-2, 1 barrier/phase ----
__global__ void __launch_bounds__(256, 2) attn_kernel(const bf16_t* __restrict__ q,
                                                      const bf16_t* __restrict__ k,
                                                      const bf16_t* __restrict__ vt,
                                                      bf16_t* __restrict__ attn_out) {
  __shared__ char Ks[4][8192];   // [64 key][64 d] bf16, 128B rows, 16B-chunk swizzled
  __shared__ char Vs[4][8192];   // [64 d][64 key] bf16, 128B rows, swizzled
  __shared__ char Ps[4][4096];   // per-wave P [32 q][64 key] bf16, swizzled
  const int tid = threadIdx.x;
  const int lane = tid & 63, wid = tid >> 6;
  const int lrow = lane & 15, kgrp = lane >> 4;
  const int bh = blockIdx.x, qb = blockIdx.y;
  const int b = bh >> 3, h = bh & 7;

  const char* khb = (const char*)(k + (size_t)bh * 1024 * 64);
  const char* vthb = (const char*)(vt + (size_t)bh * 64 * 1024);
  const bf16_t* qh = q + (size_t)bh * 1024 * 64;

  const int qbase = qb * 128 + wid * 32;
  bf16x8 qa[2][2];
#pragma unroll
  for (int qf = 0; qf < 2; ++qf) {
    int qrow = qbase + qf * 16 + lrow;
    qa[qf][0] = *(const bf16x8*)(qh + qrow * 64 + kgrp * 8);
    qa[qf][1] = *(const bf16x8*)(qh + qrow * 64 + 32 + kgrp * 8);
  }

  char* Pw = Ps[wid];
  const int srow = tid >> 3;
  const int sc2 = tid & 7;

  float l_part[2] = {0.f, 0.f};
  f32x4 o[2][4] = {};

#pragma unroll
  for (int p = 0; p < 2; ++p) {
    const char* kg = khb + p * (64 * 128);
    const char* vg = vthb + p * 128;
#pragma unroll
    for (int j = 0; j < 2; ++j) {
      int row = j * 32 + srow;
      gload_lds16(kg + row * 128 + ((sc2 ^ (row & 7)) * 16), Ks[p] + j * 4096 + tid * 16);
    }
#pragma unroll
    for (int j = 0; j < 2; ++j) {
      int row = j * 32 + srow;
      gload_lds16(vg + row * 2048 + ((sc2 ^ (row & 7)) * 16), Vs[p] + j * 4096 + tid * 16);
    }
  }

  for (int t = 0; t < 16; ++t) {
    const int cur = t & 3;
    if (t < 14) {
      const int nxt = (t + 2) & 3;
      const char* kg = khb + (t + 2) * (64 * 128);
      const char* vg = vthb + (t + 2) * 128;
#pragma unroll
      for (int j = 0; j < 2; ++j) {
        int row = j * 32 + srow;
        gload_lds16(kg + row * 128 + ((sc2 ^ (row & 7)) * 16),
                    Ks[nxt] + j * 4096 + tid * 16);
      }
#pragma unroll
      for (int j = 0; j < 2; ++j) {
        int row = j * 32 + srow;
        gload_lds16(vg + row * 2048 + ((sc2 ^ (row & 7)) * 16),
                    Vs[nxt] + j * 4096 + tid * 16);
      }
      asm volatile("s_waitcnt vmcnt(8)" ::: "memory");
    } else if (t == 14) {
      asm volatile("s_waitcnt vmcnt(4)" ::: "memory");
    } else {
      asm volatile("s_waitcnt vmcnt(0)" ::: "memory");
    }
    __builtin_amdgcn_sched_barrier(0);
    __builtin_amdgcn_s_barrier();

    const char* Kc = Ks[cur];
    const char* Vc = Vs[cur];

    f32x4 sa[2][4] = {};
    __builtin_amdgcn_s_setprio(1);
#pragma unroll
    for (int c = 0; c < 4; ++c) {
      int krow = c * 16 + lrow;
      bf16x8 k0 = *(const bf16x8*)(Kc + krow * 128 + ((kgrp ^ (krow & 7)) * 16));
      bf16x8 k1 = *(const bf16x8*)(Kc + krow * 128 + (((4 + kgrp) ^ (krow & 7)) * 16));
#pragma unroll
      for (int qf = 0; qf < 2; ++qf) {
        sa[qf][c] = __builtin_amdgcn_mfma_f32_16x16x32_bf16(k0, qa[qf][0], sa[qf][c], 0, 0, 0);
        sa[qf][c] = __builtin_amdgcn_mfma_f32_16x16x32_bf16(k1, qa[qf][1], sa[qf][c], 0, 0, 0);
      }
    }
    __builtin_amdgcn_s_setprio(0);

#pragma unroll
    for (int qf = 0; qf < 2; ++qf) {
      int prow = qf * 16 + lrow;
      float rs = 0.f;
#pragma unroll
      for (int c = 0; c < 4; ++c) {
        bf16x4 pk;
#pragma unroll
        for (int r = 0; r < 4; ++r) {
          float p = exp2f(sa[qf][c][r]);
          rs += p;
          pk[r] = (bf16_t)p;
        }
        int chunk = (c * 2 + (kgrp >> 1)) ^ (prow & 7);
        *(bf16x4*)(Pw + prow * 128 + chunk * 16 + (kgrp & 1) * 8) = pk;
      }
      l_part[qf] += rs;
    }

    __builtin_amdgcn_s_setprio(1);
#pragma unroll
    for (int kk = 0; kk < 2; ++kk) {
      bf16x8 pa[2];
#pragma unroll
      for (int qf = 0; qf < 2; ++qf) {
        int prow = qf * 16 + lrow;
        int pchunk = (kk * 4 + kgrp) ^ (prow & 7);
        pa[qf] = *(const bf16x8*)(Pw + prow * 128 + pchunk * 16);
      }
#pragma unroll
      for (int nfo = 0; nfo < 4; ++nfo) {
        int vrow = nfo * 16 + lrow;
        int vchunk = (kk * 4 + kgrp) ^ (vrow & 7);
        bf16x8 vb = *(const bf16x8*)(Vc + vrow * 128 + vchunk * 16);
#pragma unroll
        for (int qf = 0; qf < 2; ++qf)
          o[qf][nfo] = __builtin_amdgcn_mfma_f32_16x16x32_bf16(pa[qf], vb, o[qf][nfo], 0, 0, 0);
      }
    }
    __builtin_amdgcn_s_setprio(0);
  }

#pragma unroll
  for (int qf = 0; qf < 2; ++qf) {
    l_part[qf] += __shfl_xor(l_part[qf], 16, 64);
    l_part[qf] += __shfl_xor(l_part[qf], 32, 64);
  }
#pragma unroll
  for (int qf = 0; qf < 2; ++qf)
#pragma unroll
    for (int r = 0; r < 4; ++r) {
      float inv = 1.0f / __shfl(l_part[qf], kgrp * 4 + r, 64);
      int s = qbase + qf * 16 + kgrp * 4 + r;
#pragma unroll
      for (int nfo = 0; nfo < 4; ++nfo) {
        int d = nfo * 16 + lrow;
        attn_out[((b * 1024 + s) * 8 + h) * 64 + d] = (bf16_t)(o[qf][nfo][r] * inv);
      }
    }
}

// ---------------- out-proj (transposed): woT x attn + x -> out ----------------
__global__ void __launch_bounds__(256, 2) gemm_out_kernel(const bf16_t* __restrict__ woT,
                                                          const bf16_t* __restrict__ attn,
                                                          const float* __restrict__ x,
                                                          const float* __restrict__ bo,
                                                          float* __restrict__ out) {
  __shared__ bf16_t As[4][128 * 32];
  __shared__ bf16_t Bs[4][128 * 32];
  const int bn = blockIdx.x, bm = blockIdx.y;
  f32x4 acc[4][4] = {};
  gemm_nt_128x128_p4(woT + bm * 128 * 512, attn + bn * 128 * 512, As, Bs, acc);
  const int lane = threadIdx.x & 63, wid = threadIdx.x >> 6;
  const int wr = wid >> 1, wc = wid & 1;
  const int c0 = bm * 128 + wr * 64;
  const int s0g = bn * 128 + wc * 64;
#pragma unroll
  for (int mf = 0; mf < 4; ++mf)
#pragma unroll
    for (int r = 0; r < 4; ++r) {
      int c = c0 + mf * 16 + (lane >> 4) * 4 + r;
      float bias = bo[c];
#pragma unroll
      for (int nf = 0; nf < 4; ++nf) {
        int n = s0g + nf * 16 + (lane & 15);
        int b = n >> 10, s = n & 1023;
        int idx = (b * 512 + c) * 1024 + s;
        out[idx] = x[idx] + acc[mf][nf][r] + bias;
      }
    }
}

extern "C" void kernel_launch(void* const* d_in, const int* in_sizes, int n_in,
                              void* d_out, int out_size, void* d_ws, size_t ws_size,
                              hipStream_t stream) {
  const float* x  = (const float*)d_in[0];
  const float* wq = (const float*)d_in[1];
  const float* bq = (const float*)d_in[2];
  const float* wk = (const float*)d_in[3];
  const float* bk = (const float*)d_in[4];
  const float* wv = (const float*)d_in[5];
  const float* bv = (const float*)d_in[6];
  const float* wo = (const float*)d_in[7];
  const float* bo = (const float*)d_in[8];
  float* out = (float*)d_out;

  char* ws = (char*)d_ws;
  const size_t SZ_XR = (size_t)8192 * 512 * 2;         // 8 MB
  const size_t SZ_W  = (size_t)512 * 512 * 2;          // 0.5 MB
  const size_t SZ_T  = (size_t)8 * 8 * 1024 * 64 * 2;  // 8 MB
  bf16_t* xr   = (bf16_t*)(ws);                        // dead after QKV GEMM
  bf16_t* wqT  = (bf16_t*)(ws + SZ_XR);                // wqT,wkT,wvT contiguous [1536][512]
  bf16_t* wkT  = (bf16_t*)(ws + SZ_XR + SZ_W);
  bf16_t* wvT  = (bf16_t*)(ws + SZ_XR + 2 * SZ_W);
  bf16_t* woT  = (bf16_t*)(ws + SZ_XR + 3 * SZ_W);
  bf16_t* qd   = (bf16_t*)(ws + SZ_XR + 4 * SZ_W);
  bf16_t* kd   = (bf16_t*)(ws + SZ_XR + 4 * SZ_W + SZ_T);
  bf16_t* vtd  = (bf16_t*)(ws + SZ_XR + 4 * SZ_W + 2 * SZ_T);
  bf16_t* attn = (bf16_t*)(ws);                        // alias xr (dead by attn time)

  prep_kernel<<<dim3(5120), dim3(32, 8), 0, stream>>>(x, wq, wk, wv, wo, xr, wqT, wkT,
                                                      wvT, woT);
  gemm_qkv_kernel<<<dim3(6, 64), 256, 0, stream>>>(xr, wqT, bq, bk, bv, qd, kd, vtd);
  attn_kernel<<<dim3(64, 8), 256, 0, stream>>>(qd, kd, vtd, attn);
  gemm_out_kernel<<<dim3(64, 4), 256, 0, stream>>>(woT, attn, x, bo, out);
}